// Round 4
// baseline (1936.157 us; speedup 1.0000x reference)
//
#include <hip/hip_runtime.h>
#include <stdint.h>

#define T_DIM 512
#define B_DIM 256
#define OBS_DIM 128
#define H_DIM 256
#define A_DIM 32
#define TB (T_DIM*B_DIM)   // 131072
#define SR 4               // batch rows per scan block

typedef unsigned short u16;
typedef unsigned int   u32;
typedef _Float16 half2v __attribute__((ext_vector_type(2)));
typedef _Float16 f16x8 __attribute__((ext_vector_type(8)));  // MFMA A/B frag (4 VGPRs)
typedef __attribute__((ext_vector_type(8))) short short8;    // 8 bf16 (4 VGPRs)
typedef __attribute__((ext_vector_type(4))) float f32x4;
typedef __attribute__((ext_vector_type(4))) u32   u32x4;

__device__ __forceinline__ float bf2f(u16 v){ return __uint_as_float(((u32)v)<<16); }
__device__ __forceinline__ u16 f2bf(float f){
    u32 x = __float_as_uint(f);
    u32 r = x + 0x7fffu + ((x>>16)&1u);   // round-to-nearest-even
    return (u16)(r>>16);
}
__device__ __forceinline__ float2 bfpair(u32 u){
    return make_float2(__uint_as_float(u<<16), __uint_as_float(u & 0xffff0000u));
}

// ---------------------------------------------------------------------------
// dones dtype probe (u8 bool vs i32 vs f32) via nonzero byte positions mod 4.
// ---------------------------------------------------------------------------
__global__ void zero_flags_kernel(int* p){ if(threadIdx.x<4) p[threadIdx.x]=0; }

__global__ void detect_kernel(const unsigned char* __restrict__ d, int n, int* __restrict__ flags){
    int f=0;
    for(int p = blockIdx.x*blockDim.x+threadIdx.x; p<n; p += gridDim.x*blockDim.x){
        if(d[p]){ int m=p&3; if(m==1) f|=1; else if(m>=2) f|=2; }
    }
    if(f) atomicOr(flags, f);
}

// concat b_a1(256) | b_c1(256) -> b_ac(512) for the fused head-1 GEMM
__global__ void concat_bias_kernel(const float* __restrict__ a, const float* __restrict__ b,
                                   float* __restrict__ dst){
    int i = threadIdx.x;
    dst[i] = a[i];
    dst[256 + i] = b[i];
}

// ---------------------------------------------------------------------------
// Recurrent weights -> f16 W^T combined [768][256]:
// row g = m*256 + j (gate-col: 0-255 r, 256-511 z, 512-767 n), col = k.
// dst[(m*256+j)*256 + k] = (f16) W_m[k][j]
// ---------------------------------------------------------------------------
__global__ void cvt_wT3_f16_kernel(const float* __restrict__ Whr, const float* __restrict__ Whz,
                                   const float* __restrict__ Whn, _Float16* __restrict__ dst){
    int i = blockIdx.x*blockDim.x + threadIdx.x;
    if(i >= 3*H_DIM*H_DIM) return;
    int k = i & 255;
    int j = (i >> 8) & 255;
    int m = i >> 16;
    const float* W = (m==0) ? Whr : (m==1) ? Whz : Whn;
    dst[i] = (_Float16)W[(size_t)k*H_DIM + j];
}

// GEMM weight f32 [K][N] -> bf16 transposed [N][K]
__global__ void cvt_wT_kernel(const float* __restrict__ W, u16* __restrict__ dst,
                              int K, int N){
    int i = blockIdx.x*blockDim.x + threadIdx.x;
    if(i >= K*N) return;
    int n = i / K;
    int k = i - n*K;
    dst[i] = f2bf(W[(size_t)k*N + n]);
}

// ---------------------------------------------------------------------------
// MFMA bf16 GEMM: C[M,N](bf16) = opt_relu(A @ Bt^T + bias), Bt bf16 [N][K].
// A is bf16 (AF32=0) or f32 converted during staging (AF32=1).
// 128x128 tile, BK=32, 4 waves 2x2, 16x mfma_f32_16x16x32_bf16 each.
// ---------------------------------------------------------------------------
template<int RELU, int AF32>
__global__ __launch_bounds__(256, 2)
void gemm_mfma_kernel(const void* __restrict__ A_, const u16* __restrict__ Bt,
                      const float* __restrict__ bias, u16* __restrict__ C,
                      int M, int N, int K)
{
    __shared__ u16 As[128*32];
    __shared__ u16 Bs[128*32];
    const int tid  = threadIdx.x;
    const int wave = tid >> 6;
    const int lane = tid & 63;
    const int ln15 = lane & 15;
    const int quad = lane >> 4;
    const int wm = wave & 1, wn = wave >> 1;
    const int rowBase = blockIdx.y*128;
    const int colBase = blockIdx.x*128;

    f32x4 acc[4][4] = {};

    const int sr = tid >> 1;
    const int sc = (tid & 1) * 16;

    for(int kb = 0; kb < K; kb += 32){
        if(AF32){
            const float* af = (const float*)A_;
            const float* ag = af + (size_t)(rowBase+sr)*K + kb + sc;
            float4 f0 = *(const float4*)ag;
            float4 f1 = *(const float4*)(ag+4);
            float4 f2 = *(const float4*)(ag+8);
            float4 f3 = *(const float4*)(ag+12);
            u16 tmp[16] = { f2bf(f0.x),f2bf(f0.y),f2bf(f0.z),f2bf(f0.w),
                            f2bf(f1.x),f2bf(f1.y),f2bf(f1.z),f2bf(f1.w),
                            f2bf(f2.x),f2bf(f2.y),f2bf(f2.z),f2bf(f2.w),
                            f2bf(f3.x),f2bf(f3.y),f2bf(f3.z),f2bf(f3.w) };
            *(uint4*)&As[sr*32 + sc]     = *(const uint4*)&tmp[0];
            *(uint4*)&As[sr*32 + sc + 8] = *(const uint4*)&tmp[8];
        } else {
            const u16* ab = (const u16*)A_;
            const u16* ag = ab + (size_t)(rowBase+sr)*K + kb + sc;
            uint4 av0 = *(const uint4*)ag;
            uint4 av1 = *(const uint4*)(ag+8);
            *(uint4*)&As[sr*32 + sc]     = av0;
            *(uint4*)&As[sr*32 + sc + 8] = av1;
        }
        {
            const u16* bg = Bt + (size_t)(colBase+sr)*K + kb + sc;
            uint4 bv0 = *(const uint4*)bg;
            uint4 bv1 = *(const uint4*)(bg+8);
            *(uint4*)&Bs[sr*32 + sc]     = bv0;
            *(uint4*)&Bs[sr*32 + sc + 8] = bv1;
        }
        __syncthreads();

        short8 af[4], bf[4];
        #pragma unroll
        for(int mt=0;mt<4;mt++)
            af[mt] = *(const short8*)&As[(wm*64+mt*16+ln15)*32 + quad*8];
        #pragma unroll
        for(int nt=0;nt<4;nt++)
            bf[nt] = *(const short8*)&Bs[(wn*64+nt*16+ln15)*32 + quad*8];
        #pragma unroll
        for(int mt=0;mt<4;mt++){
            #pragma unroll
            for(int nt=0;nt<4;nt++){
                acc[mt][nt] = __builtin_amdgcn_mfma_f32_16x16x32_bf16(
                                  af[mt], bf[nt], acc[mt][nt], 0, 0, 0);
            }
        }
        __syncthreads();
    }

    #pragma unroll
    for(int nt=0;nt<4;nt++){
        int n = colBase + wn*64 + nt*16 + ln15;
        float bv = bias[n];
        #pragma unroll
        for(int mt=0;mt<4;mt++){
            #pragma unroll
            for(int r=0;r<4;r++){
                int m = rowBase + wm*64 + mt*16 + quad*4 + r;
                float v = acc[mt][nt][r] + bv;
                if(RELU) v = fmaxf(v, 0.f);
                C[(size_t)m*N + n] = f2bf(v);
            }
        }
    }
}

// ---------------------------------------------------------------------------
// MFMA GRU scan. R1-R3 lesson: v_dot2 (VOP3P) cannot read AGPRs, so the
// allocator's AGPR-parking of persistent weight arrays costs one
// v_accvgpr_read per dot -- unfixable at source level. MFMA reads A/B
// operands FROM AGPRs natively, so parking becomes free.
//
// 64 blocks x SR=4 batch rows, 512 threads (8 waves, 2/SIMD, 256-reg budget).
// Wave w owns col-tiles {2w, 2w+1} (16 cols each) for all three gates:
// 2x3x8 = 48 f16x8 B-frags = 192 regs parked + 24 acc. Per step:
//   prefetch gi gate inputs -> 8x swizzled ds_read_b128 of h (A-frags, rows
//   4-15 zeroed) -> 48 mfma/wave -> quad0 writes valid acc rows to padded
//   accb -> barrier -> uniform gate phase (2 gates/thread, f32 hreg carry,
//   exactly the old numerics: f16 inputs, f32 accum/gates) -> barrier.
// ---------------------------------------------------------------------------
__global__ __attribute__((amdgpu_flat_work_group_size(512,512), amdgpu_waves_per_eu(2,2)))
void scan_kernel(const u16* __restrict__ gi, const void* __restrict__ dones,
                 const int* __restrict__ flags, const _Float16* __restrict__ WT,
                 const float* __restrict__ bhn, float* __restrict__ h_carry,
                 u16* __restrict__ y, int t0, int Tc)
{
    __shared__ _Float16 h_lds[16*256];        // 8 KB; 16B-chunk XOR swizzle
    __shared__ float accb[3][256][6];         // 18 KB; pad-6 breaks bank stride
    __shared__ unsigned char dn_lds[64][SR];  // dones per (step, local row)

    const int tid  = threadIdx.x;
    const int wave = tid >> 6;      // 0..7
    const int lane = tid & 63;
    const int ln15 = lane & 15;
    const int quad = lane >> 4;
    const int rb   = blockIdx.x * SR;
    const int fl   = flags[0];
    const int mode = (fl&1) ? 0 : ((fl&2) ? 2 : 1);  // 0=u8, 1=i32, 2=f32

    // ---- one-time B-frag load: cols of W^T for this wave's 2 tiles ----
    f16x8 wf[2][3][8];
    {
        const f16x8* Wv = (const f16x8*)WT;   // [768][32] f16x8 units
        #pragma unroll
        for(int s=0;s<2;s++){
            int col = (wave*2+s)*16 + ln15;
            #pragma unroll
            for(int m=0;m<3;m++){
                #pragma unroll
                for(int kk=0;kk<8;kk++)
                    wf[s][m][kk] = Wv[(size_t)(m*256 + col)*32 + kk*4 + quad];
            }
        }
    }

    // ---- stage dones for the chunk; zero unused h rows 4..15 ----
    if(tid < Tc*SR){
        int tt = tid >> 2, r = tid & 3;
        int idx = (t0+tt)*B_DIM + rb + r;
        bool d;
        if(mode==0)      d = ((const unsigned char*)dones)[idx] != 0;
        else if(mode==1) d = ((const int*)dones)[idx] != 0;
        else             d = ((const float*)dones)[idx] != 0.f;
        dn_lds[tt][r] = d ? 1 : 0;
    }
    for(int i = 1024 + tid; i < 4096; i += 512) h_lds[i] = (_Float16)0.f;
    __syncthreads();

    // ---- gate ownership: col = tid&255, rows {2rp, 2rp+1} ----
    const int col = tid & 255;
    const int rp  = tid >> 8;
    const float bh = bhn[col];
    float hreg[2];
    #pragma unroll
    for(int e=0;e<2;e++){
        int row = rp*2 + e;
        bool d0 = dn_lds[0][row] != 0;
        hreg[e] = d0 ? 0.f : h_carry[(size_t)(rb+row)*H_DIM + col];
        h_lds[row*256 + (((col>>3) ^ row)<<3) + (col&7)] = (_Float16)hreg[e];
    }
    __syncthreads();

    for(int t=0; t<Tc; ++t){
        // gate-input prefetch (consumed ~500cyc later, after the mfma phase)
        size_t gb = ((size_t)t*B_DIM + rb)*768;
        float giv[2][3];
        #pragma unroll
        for(int e=0;e<2;e++){
            size_t ro = gb + (size_t)(rp*2+e)*768;
            giv[e][0] = bf2f(gi[ro + col]);
            giv[e][1] = bf2f(gi[ro + 256 + col]);
            giv[e][2] = bf2f(gi[ro + 512 + col]);
        }

        // ---- MFMA phase: 48 mfma, A = h rows (swizzled LDS read) ----
        f32x4 acc[2][3] = {};
        #pragma unroll
        for(int kk=0;kk<8;kk++){
            f16x8 hv = *(const f16x8*)&h_lds[ln15*256 + (((kk*4+quad) ^ (ln15&7))<<3)];
            #pragma unroll
            for(int s=0;s<2;s++){
                acc[s][0] = __builtin_amdgcn_mfma_f32_16x16x32_f16(hv, wf[s][0][kk], acc[s][0], 0,0,0);
                acc[s][1] = __builtin_amdgcn_mfma_f32_16x16x32_f16(hv, wf[s][1][kk], acc[s][1], 0,0,0);
                acc[s][2] = __builtin_amdgcn_mfma_f32_16x16x32_f16(hv, wf[s][2][kk], acc[s][2], 0,0,0);
            }
        }

        // ---- exchange: only rows 0..3 (quad 0) are real ----
        if(quad == 0){
            #pragma unroll
            for(int s=0;s<2;s++){
                int c = (wave*2+s)*16 + ln15;
                #pragma unroll
                for(int m=0;m<3;m++){
                    *(float2*)&accb[m][c][0] = make_float2(acc[s][m][0], acc[s][m][1]);
                    *(float2*)&accb[m][c][2] = make_float2(acc[s][m][2], acc[s][m][3]);
                }
            }
        }
        __syncthreads();

        // ---- gate phase: 2 gates/thread, f32 ----
        #pragma unroll
        for(int e=0;e<2;e++){
            int row = rp*2 + e;
            float rt  = accb[0][col][row];
            float zt  = accb[1][col][row];
            float ntv = accb[2][col][row];
            float r = 1.f/(1.f + __expf(-(giv[e][0] + rt)));
            float z = 1.f/(1.f + __expf(-(giv[e][1] + zt)));
            float x = giv[e][2] + r*(ntv + bh);
            float e2 = __expf(2.f*x);
            float n = 1.f - 2.f/(e2 + 1.f);          // tanh(x)
            float hn = (1.f - z)*n + z*hreg[e];
            y[((size_t)t*B_DIM + rb + row)*H_DIM + col] = f2bf(hn);
            bool dn = (t < Tc-1) ? (dn_lds[t+1][row] != 0) : false;
            hreg[e] = dn ? 0.f : hn;
            h_lds[row*256 + (((col>>3) ^ row)<<3) + (col&7)] = (_Float16)hreg[e];
        }
        __syncthreads();
    }

    #pragma unroll
    for(int e=0;e<2;e++)
        h_carry[(size_t)(rb + rp*2 + e)*H_DIM + col] = hreg[e];  // raw carry
}

// ---------------------------------------------------------------------------
// Actor head stage 2: logits[rows,32] = ah[rows,:256 of ld] @ W_a2 + b_a2 - (1-avail)*1e10
// ---------------------------------------------------------------------------
__global__ __launch_bounds__(256)
void actor2_kernel(const u16* __restrict__ ah, int ld, const float* __restrict__ W_a2,
                   const float* __restrict__ b_a2, const float* __restrict__ avail,
                   float* __restrict__ logits)
{
    __shared__ u16 ahs[64][264];
    const int tid = threadIdx.x;
    const int r0 = blockIdx.x*64;
    {
        int row = tid & 63;
        int c0 = (tid >> 6) * 64;
        const uint4* gp = (const uint4*)(ah + (size_t)(r0+row)*ld + c0);
        #pragma unroll
        for(int q=0;q<8;q++){
            uint4 u = gp[q];
            u32* dst = (u32*)&ahs[row][c0 + q*8];
            dst[0]=u.x; dst[1]=u.y; dst[2]=u.z; dst[3]=u.w;
        }
    }
    __syncthreads();
    const int c  = tid & 31;
    const int rg = tid >> 5;   // 0..7
    float acc[8]={0.f,0.f,0.f,0.f,0.f,0.f,0.f,0.f};
    float bc = b_a2[c];
    for(int k=0;k<H_DIM;k+=4){
        float w0 = W_a2[(k+0)*A_DIM + c];
        float w1 = W_a2[(k+1)*A_DIM + c];
        float w2 = W_a2[(k+2)*A_DIM + c];
        float w3 = W_a2[(k+3)*A_DIM + c];
        #pragma unroll
        for(int rr=0;rr<8;rr++){
            uint2 av = *(const uint2*)&ahs[rg*8+rr][k];
            float2 p0 = bfpair(av.x), p1 = bfpair(av.y);
            acc[rr] = fmaf(p0.x,w0,fmaf(p0.y,w1,fmaf(p1.x,w2,fmaf(p1.y,w3,acc[rr]))));
        }
    }
    #pragma unroll
    for(int rr=0;rr<8;rr++){
        int grow = r0 + rg*8 + rr;
        float av = avail[(size_t)grow*A_DIM + c];
        logits[(size_t)grow*A_DIM + c] = acc[rr] + bc - (1.f-av)*1e10f;
    }
}

// ---------------------------------------------------------------------------
// Critic head stage 2: value[row] = ch[row,:256 of ld] @ W_c2 + b_c2. Wave per row.
// ---------------------------------------------------------------------------
__global__ __launch_bounds__(256)
void critic2_kernel(const u16* __restrict__ ch, int ld, const float* __restrict__ W_c2,
                    const float* __restrict__ b_c2, float* __restrict__ value)
{
    const int lane = threadIdx.x & 63;
    const int wid  = threadIdx.x >> 6;
    const int row  = blockIdx.x*4 + wid;
    uint2 av = *(const uint2*)(ch + (size_t)row*ld + lane*4);
    float2 p0 = bfpair(av.x), p1 = bfpair(av.y);
    float4 wv = *(const float4*)(W_c2 + lane*4);
    float acc = p0.x*wv.x + p0.y*wv.y + p1.x*wv.z + p1.y*wv.w;
    #pragma unroll
    for(int off=32; off>0; off>>=1) acc += __shfl_down(acc, off, 64);
    if(lane==0) value[row] = acc + b_c2[0];
}

// ---------------------------------------------------------------------------
extern "C" void kernel_launch(void* const* d_in, const int* in_sizes, int n_in,
                              void* d_out, int out_size, void* d_ws, size_t ws_size,
                              hipStream_t stream)
{
    const float* hidden = (const float*)d_in[0];
    const float* obs    = (const float*)d_in[1];
    const void*  dones  = d_in[2];
    const float* avail  = (const float*)d_in[3];
    const float* W_emb  = (const float*)d_in[4];
    const float* b_emb  = (const float*)d_in[5];
    const float* Wi     = (const float*)d_in[6];
    const float* bi     = (const float*)d_in[7];
    const float* Whr    = (const float*)d_in[8];
    const float* Whz    = (const float*)d_in[9];
    const float* Whn    = (const float*)d_in[10];
    const float* bhn    = (const float*)d_in[11];
    const float* W_a1   = (const float*)d_in[12];
    const float* b_a1   = (const float*)d_in[13];
    const float* W_a2   = (const float*)d_in[14];
    const float* b_a2   = (const float*)d_in[15];
    const float* W_c1   = (const float*)d_in[16];
    const float* b_c1   = (const float*)d_in[17];
    const float* W_c2   = (const float*)d_in[18];
    const float* b_c2   = (const float*)d_in[19];

    float* out_hidden = (float*)d_out;                       // 65536
    float* out_logits = out_hidden + (size_t)B_DIM*H_DIM;    // 4194304
    float* out_value  = out_logits + (size_t)TB*A_DIM;       // 131072

    // ---- workspace layout (chunk size adapted to ws_size, deterministic) ----
    // fixed: WT(f16 scan) + wiT + wacT(fused a1|c1) + wembT + h_carry + flags + b_ac
    const size_t fixed = 393216 + 393216 + 262144 + 65536 + 262144 + 256 + 2048;
    int Tc = 4;
    for(int cand = 64; cand >= 4; cand >>= 1){
        size_t need = fixed + (size_t)cand*(393216 /*gi*/ + 262144 /*emb|ac*/ + 131072 /*y*/);
        if(need <= ws_size){ Tc = cand; break; }
    }
    const int NC = T_DIM / Tc;

    uint8_t* ws = (uint8_t*)d_ws;
    size_t off = 0;
    _Float16* wT  = (_Float16*)(ws + off); off += 393216;  // scan W^T f16 [768][256]
    u16*  wiT     = (u16*)(ws + off); off += 393216;   // Wi^T bf16 [768][256]
    u16*  wacT    = (u16*)(ws + off); off += 262144;   // [W_a1^T | W_c1^T] bf16 [512][256]
    u16*  wembT   = (u16*)(ws + off); off += 65536;    // W_emb^T bf16 [256][128]
    float* h_carry= (float*)(ws + off); off += 262144;
    int*  flags   = (int*)(ws + off); off += 256;
    float* b_ac   = (float*)(ws + off); off += 2048;   // b_a1|b_c1 (512 f32)
    u16*  gi_c    = (u16*)(ws + off); off += (size_t)Tc*393216;
    u16*  embac_c = (u16*)(ws + off); off += (size_t)Tc*262144;  // emb [Mc][256], later ac [Mc][512]
    u16*  y_c     = (u16*)(ws + off); off += (size_t)Tc*131072;
    u16*  emb_c   = embac_c;
    u16*  ac_c    = embac_c;

    zero_flags_kernel<<<1, 64, 0, stream>>>(flags);
    detect_kernel<<<64, 256, 0, stream>>>((const unsigned char*)dones, TB, flags);
    cvt_wT3_f16_kernel<<<768, 256, 0, stream>>>(Whr, Whz, Whn, wT);
    cvt_wT_kernel<<<768, 256, 0, stream>>>(Wi,   wiT,  256, 768);
    cvt_wT_kernel<<<256, 256, 0, stream>>>(W_a1, wacT,          256, 256);
    cvt_wT_kernel<<<256, 256, 0, stream>>>(W_c1, wacT + 65536,  256, 256);
    cvt_wT_kernel<<<128, 256, 0, stream>>>(W_emb, wembT, 128, 256);
    concat_bias_kernel<<<1, 256, 0, stream>>>(b_a1, b_c1, b_ac);
    hipMemcpyAsync(h_carry, hidden, (size_t)B_DIM*H_DIM*sizeof(float),
                   hipMemcpyDeviceToDevice, stream);

    const int Mc = Tc*B_DIM;
    const int gy = Mc/128;

    for(int c = 0; c < NC; ++c){
        const int t0 = c*Tc;
        const float* obs_c = obs + (size_t)t0*B_DIM*OBS_DIM;
        // emb = relu(obs @ W_emb + b_emb)  (MFMA, f32 A converted in staging)
        gemm_mfma_kernel<1,1><<<dim3(2,gy), 256, 0, stream>>>(obs_c, wembT, b_emb, emb_c, Mc, 256, 128);
        // gi = emb @ Wi + bi  (MFMA)
        gemm_mfma_kernel<0,0><<<dim3(6,gy), 256, 0, stream>>>(emb_c, wiT, bi, gi_c, Mc, 768, 256);
        // GRU scan chunk: 64 blocks (4 batch rows each) x 512 threads, MFMA
        scan_kernel<<<B_DIM/SR, 512, 0, stream>>>(gi_c, dones, flags, wT,
                                                  bhn, h_carry, y_c, t0, Tc);
        // fused actor1|critic1 head: [Mc][512] = relu(y @ [W_a1|W_c1] + b_ac)
        gemm_mfma_kernel<1,0><<<dim3(4,gy), 256, 0, stream>>>(y_c, wacT, b_ac, ac_c, Mc, 512, 256);
        actor2_kernel<<<Mc/64, 256, 0, stream>>>(ac_c, 512, W_a2, b_a2,
                                                 avail + (size_t)t0*B_DIM*A_DIM,
                                                 out_logits + (size_t)t0*B_DIM*A_DIM);
        critic2_kernel<<<Mc/4, 256, 0, stream>>>(ac_c + 256, 512, W_c2, b_c2,
                                                 out_value + (size_t)t0*B_DIM);
    }

    hipMemcpyAsync(out_hidden, h_carry, (size_t)B_DIM*H_DIM*sizeof(float),
                   hipMemcpyDeviceToDevice, stream);
}